// Round 6
// baseline (249.014 us; speedup 1.0000x reference)
//
#include <hip/hip_runtime.h>

#define KS 41
#define PAD 20
#define H 512
#define W 512
#define CH 6

// Transposed-output horizontal blur tile geometry
#define TR 64                  // tile rows (lane = row)
#define TC 64                  // tile cols (output cols per block)
#define PC (TC + 2 * PAD)      // 104 padded cols
#define LSTR 65                // LDS row stride; 65 % 32 == 1 -> conflict-free both ways
#define WCOL 16                // cols per wave (4 waves)
#define CWIN (WCOL + 2 * PAD)  // 56-float sliding register window (fits VGPRs)

__device__ __forceinline__ int reflect_idx(int i, int n) {
    if (i < 0) i = -i;
    if (i >= n) i = 2 * n - 2 - i;
    return i;
}

__device__ __forceinline__ int reflect511(int i) {
    // valid for i in (-512, 1022); H == W == 512
    return (H - 1) - abs((H - 1) - abs(i));
}

__device__ __forceinline__ float uniform_f(float v) {
    return __uint_as_float(__builtin_amdgcn_readfirstlane(__float_as_uint(v)));
}

// Coefficients -> SGPRs, no LDS, no barrier: lane j (j<41) computes row-sum j
// of the separable 2D kernel (== normalized 1D gaussian), readlane broadcasts.
__device__ __forceinline__ void load_coeffs(const float* __restrict__ w, int c,
                                            int lane, float gk[KS]) {
    float my = 0.f;
    if (lane < KS) {
        const float* wr = w + (size_t)c * KS * KS + (size_t)lane * KS;
        #pragma unroll
        for (int j = 0; j < KS; ++j) my += wr[j];
    }
    #pragma unroll
    for (int j = 0; j < KS; ++j)
        gk[j] = __uint_as_float(__builtin_amdgcn_readlane(__float_as_uint(my), j));
}

// Horizontal blur with TRANSPOSED output: outT[c][r] = sum_j g[j]*in[r][refl(c-20+j)].
// Applied twice == full separable blur, final orientation restored.
// All LDS traffic is b32 at 4B lane stride (2 lanes/bank = free, m136):
//   staging writes tmp[p*65+r]: consecutive lanes -> p+1 -> bank+1
//   compute reads  tmp[i*65+l]: consecutive lanes -> r+1 -> bank+1
// Global: reads 4B-stride coalesced; stores 256B contiguous per instruction.
// TC=64/WCOL=16 so the 56-float register window actually materializes
// (round-5's col[72] exceeded the compiler's VGPR choice -> remat tax).
__global__ __launch_bounds__(256, 5)
void hblurT_kernel(const float* __restrict__ in, const float* __restrict__ w,
                   float* __restrict__ outT) {
    __shared__ float tmp[PC * LSTR];   // 27040 B -> 5 blocks/CU

    const int tid = threadIdx.x;
    const int wv  = tid >> 6;
    const int l   = tid & 63;
    const int img = blockIdx.z;            // 0..95
    const int c   = img % CH;
    const int c0  = blockIdx.x * TC;       // 0..448
    const int r0  = blockIdx.y * TR;       // 0..448

    float gk[KS];
    load_coeffs(w, c, l, gk);

    // stage 64 rows x 104 padded cols, transposed into LDS (26 exact iters)
    const float* ip = in + (size_t)img * H * W;
    #pragma unroll
    for (int k = 0; k < (TR * PC) / 256; ++k) {
        const int t = k * 256 + tid;
        const int r = t / PC;
        const int p = t - r * PC;
        tmp[p * LSTR + r] = ip[(size_t)(r0 + r) * W + reflect511(c0 - PAD + p)];
    }
    __syncthreads();

    // wave wv -> output cols c0 + 16*wv .. +15 ; lane l -> row r0 + l
    float col[CWIN];
    #pragma unroll
    for (int i = 0; i < CWIN; ++i)
        col[i] = tmp[(WCOL * wv + i) * LSTR + l];

    float* op = outT + (size_t)img * H * W + (size_t)(c0 + WCOL * wv) * H + r0 + l;
    #pragma unroll
    for (int u = 0; u < WCOL; ++u) {
        float s = 0.f;
        #pragma unroll
        for (int j = 0; j < KS; ++j) s += gk[j] * col[u + j];
        op[(size_t)u * H] = s;   // lanes contiguous: 256B/instruction
    }
}

// ---------------- Fallback: known-correct fused kernel ----------------
#define TW 64
#define TH 128
#define TMPH (TH + 2 * PAD)  // 168

__global__ __launch_bounds__(256, 3)
void gauss_blur_fused_kernel(const float* __restrict__ x,
                             const float* __restrict__ w,
                             float* __restrict__ out) {
    __shared__ float g_s[KS];
    __shared__ float tmp[TMPH * TW];

    const int tid = threadIdx.x;
    const int bx = blockIdx.x, by = blockIdx.y, bz = blockIdx.z;
    const int c = bz % CH;

    if (tid < KS) {
        const float* wr = w + (size_t)c * KS * KS + (size_t)tid * KS;
        float s = 0.f;
        #pragma unroll
        for (int j = 0; j < KS; ++j) s += wr[j];
        g_s[tid] = s;
    }
    __syncthreads();

    float gr[KS];
    #pragma unroll
    for (int j = 0; j < KS; ++j) gr[j] = uniform_f(g_s[j]);

    const size_t img_off = (size_t)bz * (H * W);
    const float* img = x + img_off;
    const int x_tile = bx * TW;

    for (int gid = tid; gid < TMPH * (TW / 8); gid += 256) {
        const int r  = gid >> 3;
        const int gx = gid & 7;
        const int gy = reflect_idx(by * TH - PAD + r, H);
        const int x0 = x_tile + gx * 8;
        const float* row = img + (size_t)gy * W;

        float s[8];
        #pragma unroll
        for (int k = 0; k < 8; ++k) s[k] = 0.f;

        if (x0 >= PAD && x0 + 27 <= W - 1) {
            const float4* p = (const float4*)(row + x0 - PAD);
            #pragma unroll
            for (int m = 0; m < 12; ++m) {
                const float4 v = p[m];
                const float f[4] = {v.x, v.y, v.z, v.w};
                #pragma unroll
                for (int t = 0; t < 4; ++t) {
                    const int pos = 4 * m + t;
                    #pragma unroll
                    for (int k = 0; k < 8; ++k) {
                        const int tap = pos - k;
                        if (tap >= 0 && tap < KS) s[k] += gr[tap] * f[t];
                    }
                }
            }
        } else {
            #pragma unroll
            for (int pos = 0; pos < 48; ++pos) {
                const float f = row[reflect_idx(x0 - PAD + pos, W)];
                #pragma unroll
                for (int k = 0; k < 8; ++k) {
                    const int tap = pos - k;
                    if (tap >= 0 && tap < KS) s[k] += gr[tap] * f;
                }
            }
        }
        float* dstp = &tmp[r * TW + gx * 8];
        #pragma unroll
        for (int k = 0; k < 8; ++k) dstp[k] = s[k];
    }
    __syncthreads();

    const int lx = tid & 63;
    const int yg = tid >> 6;
    float* o = out + img_off;

    #pragma unroll
    for (int cc = 0; cc < 2; ++cc) {
        const int yc = yg * 32 + cc * 16;
        float col[56];
        #pragma unroll
        for (int i = 0; i < 56; ++i)
            col[i] = tmp[(yc + i) * TW + lx];
        #pragma unroll
        for (int y = 0; y < 16; ++y) {
            float s = 0.f;
            #pragma unroll
            for (int j = 0; j < KS; ++j) s += gr[j] * col[y + j];
            o[(size_t)(by * TH + yc + y) * W + x_tile + lx] = s;
        }
    }
}

extern "C" void kernel_launch(void* const* d_in, const int* in_sizes, int n_in,
                              void* d_out, int out_size, void* d_ws, size_t ws_size,
                              hipStream_t stream) {
    const float* x = (const float*)d_in[0];   // [16,6,512,512]
    const float* w = (const float*)d_in[1];   // [6,1,41,41]
    float* out = (float*)d_out;
    (void)in_sizes; (void)n_in; (void)out_size;

    const size_t need = (size_t)16 * CH * H * W * sizeof(float);
    if (ws_size >= need) {
        float* ws = (float*)d_ws;
        const dim3 grid(W / TC, H / TR, 16 * CH);   // (8, 8, 96)
        hblurT_kernel<<<grid, 256, 0, stream>>>(x,  w, ws);   // x -> hblur^T
        hblurT_kernel<<<grid, 256, 0, stream>>>(ws, w, out);  // -> full blur, normal orientation
    } else {
        dim3 grid(W / TW, H / TH, 16 * CH);
        gauss_blur_fused_kernel<<<grid, 256, 0, stream>>>(x, w, out);
    }
}

// Round 8
// 234.443 us; speedup vs baseline: 1.0622x; 1.0622x over previous
//
#include <hip/hip_runtime.h>

#define KS 41
#define PAD 20
#define H 512
#define W 512
#define CH 6

// Transposed-output horizontal blur tile geometry
#define TR 64                  // tile rows (lane = row)
#define TC 64                  // tile cols (output cols per block)
#define PC (TC + 2 * PAD)      // 104 padded cols
#define LSTR 65                // LDS row stride; 65 % 32 == 1 -> conflict-free both ways
#define WCOL 16                // cols per wave (4 waves)
#define CWIN (WCOL + 2 * PAD)  // 56-float window

__device__ __forceinline__ int reflect_idx(int i, int n) {
    if (i < 0) i = -i;
    if (i >= n) i = 2 * n - 2 - i;
    return i;
}

__device__ __forceinline__ int reflect511(int i) {
    // valid for i in (-512, 1022); H == W == 512
    return (H - 1) - abs((H - 1) - abs(i));
}

__device__ __forceinline__ float uniform_f(float v) {
    return __uint_as_float(__builtin_amdgcn_readfirstlane(__float_as_uint(v)));
}

// Fallback coeff path: lane j (j<41) computes row-sum j, readlane broadcasts.
__device__ __forceinline__ void load_coeffs(const float* __restrict__ w, int c,
                                            int lane, float gk[KS]) {
    float my = 0.f;
    if (lane < KS) {
        const float* wr = w + (size_t)c * KS * KS + (size_t)lane * KS;
        #pragma unroll
        for (int j = 0; j < KS; ++j) my += wr[j];
    }
    #pragma unroll
    for (int j = 0; j < KS; ++j)
        gk[j] = __uint_as_float(__builtin_amdgcn_readlane(__float_as_uint(my), j));
}

// Prep: 1D row-sums of the separable 2D kernel -> cbuf[c*41+j]. 6 tiny blocks.
__global__ void gauss_prep_kernel(const float* __restrict__ w,
                                  float* __restrict__ cbuf) {
    const int c = blockIdx.x;
    const int j = threadIdx.x;
    if (j < KS) {
        const float* wr = w + (size_t)c * KS * KS + (size_t)j * KS;
        float s = 0.f;
        #pragma unroll
        for (int k = 0; k < KS; ++k) s += wr[k];
        cbuf[c * KS + j] = s;
    }
}

// Horizontal blur with TRANSPOSED output: outT[c][r] = sum_j g[j]*in[r][refl(c-20+j)].
// Applied twice == full separable blur, final orientation restored.
// All LDS traffic b32 at 4B lane stride (2 lanes/bank = free).
// Staging is division-free and strength-reduced: reflected column fixed per
// thread (computed once), row marches by 2 -> global addr += 2W, ds offset imm.
template <bool GC>
__global__ __launch_bounds__(256, 6)
void hblurT_kernel(const float* __restrict__ in, const float* __restrict__ w,
                   const float* __restrict__ gc, float* __restrict__ outT) {
    __shared__ float tmp[PC * LSTR];   // 27040 B -> 6 blocks/CU

    const int tid = threadIdx.x;
    const int wv  = tid >> 6;
    const int l   = tid & 63;
    const int img = blockIdx.z;            // 0..95
    const int c   = img % CH;
    const int c0  = blockIdx.x * TC;       // 0..448
    const int r0  = blockIdx.y * TR;       // 0..448

    float gk[KS];
    if (GC) {
        const float* g = gc + c * KS;      // uniform address, precomputed sums
        #pragma unroll
        for (int j = 0; j < KS; ++j) gk[j] = uniform_f(g[j]);  // -> SGPRs
    } else {
        load_coeffs(w, c, l, gk);
    }

    // stage 64 rows x 104 padded cols, transposed into LDS
    {
        const int pcol = tid & 127;        // padded col, fixed per thread
        const int rrow = tid >> 7;         // 0 or 1; rows march by 2
        if (pcol < PC) {
            const int colr = reflect511(c0 - PAD + pcol);   // once, not per iter
            const float* gp = in + (size_t)img * H * W + (size_t)(r0 + rrow) * W + colr;
            float* lp = tmp + pcol * LSTR + rrow;
            #pragma unroll
            for (int k = 0; k < TR / 2; ++k)
                lp[2 * k] = gp[(size_t)(2 * k) * W];
        }
    }
    __syncthreads();

    // wave wv -> output cols c0 + 16*wv .. +15 ; lane l -> row r0 + l
    float col[CWIN];
    #pragma unroll
    for (int i = 0; i < CWIN; ++i)
        col[i] = tmp[(WCOL * wv + i) * LSTR + l];   // 1 v-addr + imm offsets

    float* op = outT + (size_t)img * H * W + (size_t)(c0 + WCOL * wv) * H + r0 + l;
    #pragma unroll
    for (int u = 0; u < WCOL; ++u) {
        float s = 0.f;
        #pragma unroll
        for (int j = 0; j < KS; ++j) s += gk[j] * col[u + j];
        op[(size_t)u * H] = s;   // lanes contiguous: 256B/instruction
    }
}

// ---------------- Fallback: known-correct fused kernel ----------------
#define TW 64
#define TH 128
#define TMPH (TH + 2 * PAD)  // 168

__global__ __launch_bounds__(256, 3)
void gauss_blur_fused_kernel(const float* __restrict__ x,
                             const float* __restrict__ w,
                             float* __restrict__ out) {
    __shared__ float g_s[KS];
    __shared__ float tmp[TMPH * TW];

    const int tid = threadIdx.x;
    const int bx = blockIdx.x, by = blockIdx.y, bz = blockIdx.z;
    const int c = bz % CH;

    if (tid < KS) {
        const float* wr = w + (size_t)c * KS * KS + (size_t)tid * KS;
        float s = 0.f;
        #pragma unroll
        for (int j = 0; j < KS; ++j) s += wr[j];
        g_s[tid] = s;
    }
    __syncthreads();

    float gr[KS];
    #pragma unroll
    for (int j = 0; j < KS; ++j) gr[j] = uniform_f(g_s[j]);

    const size_t img_off = (size_t)bz * (H * W);
    const float* img = x + img_off;
    const int x_tile = bx * TW;

    for (int gid = tid; gid < TMPH * (TW / 8); gid += 256) {
        const int r  = gid >> 3;
        const int gx = gid & 7;
        const int gy = reflect_idx(by * TH - PAD + r, H);
        const int x0 = x_tile + gx * 8;
        const float* row = img + (size_t)gy * W;

        float s[8];
        #pragma unroll
        for (int k = 0; k < 8; ++k) s[k] = 0.f;

        if (x0 >= PAD && x0 + 27 <= W - 1) {
            const float4* p = (const float4*)(row + x0 - PAD);
            #pragma unroll
            for (int m = 0; m < 12; ++m) {
                const float4 v = p[m];
                const float f[4] = {v.x, v.y, v.z, v.w};
                #pragma unroll
                for (int t = 0; t < 4; ++t) {
                    const int pos = 4 * m + t;
                    #pragma unroll
                    for (int k = 0; k < 8; ++k) {
                        const int tap = pos - k;
                        if (tap >= 0 && tap < KS) s[k] += gr[tap] * f[t];
                    }
                }
            }
        } else {
            #pragma unroll
            for (int pos = 0; pos < 48; ++pos) {
                const float f = row[reflect_idx(x0 - PAD + pos, W)];
                #pragma unroll
                for (int k = 0; k < 8; ++k) {
                    const int tap = pos - k;
                    if (tap >= 0 && tap < KS) s[k] += gr[tap] * f;
                }
            }
        }
        float* dstp = &tmp[r * TW + gx * 8];
        #pragma unroll
        for (int k = 0; k < 8; ++k) dstp[k] = s[k];
    }
    __syncthreads();

    const int lx = tid & 63;
    const int yg = tid >> 6;
    float* o = out + img_off;

    #pragma unroll
    for (int cc = 0; cc < 2; ++cc) {
        const int yc = yg * 32 + cc * 16;
        float col[56];
        #pragma unroll
        for (int i = 0; i < 56; ++i)
            col[i] = tmp[(yc + i) * TW + lx];
        #pragma unroll
        for (int y = 0; y < 16; ++y) {
            float s = 0.f;
            #pragma unroll
            for (int j = 0; j < KS; ++j) s += gr[j] * col[y + j];
            o[(size_t)(by * TH + yc + y) * W + x_tile + lx] = s;
        }
    }
}

extern "C" void kernel_launch(void* const* d_in, const int* in_sizes, int n_in,
                              void* d_out, int out_size, void* d_ws, size_t ws_size,
                              hipStream_t stream) {
    const float* x = (const float*)d_in[0];   // [16,6,512,512]
    const float* w = (const float*)d_in[1];   // [6,1,41,41]
    float* out = (float*)d_out;
    (void)in_sizes; (void)n_in; (void)out_size;

    const size_t need = (size_t)16 * CH * H * W * sizeof(float);
    const dim3 grid(W / TC, H / TR, 16 * CH);   // (8, 8, 96)

    if (ws_size >= need + 1024) {
        float* ws = (float*)d_ws;
        float* cbuf = ws + need / sizeof(float);            // 246 floats at tail
        gauss_prep_kernel<<<dim3(CH), 64, 0, stream>>>(w, cbuf);
        hblurT_kernel<true><<<grid, 256, 0, stream>>>(x,  w, cbuf, ws);
        hblurT_kernel<true><<<grid, 256, 0, stream>>>(ws, w, cbuf, out);
    } else if (ws_size >= need) {
        float* ws = (float*)d_ws;
        hblurT_kernel<false><<<grid, 256, 0, stream>>>(x,  w, nullptr, ws);
        hblurT_kernel<false><<<grid, 256, 0, stream>>>(ws, w, nullptr, out);
    } else {
        dim3 fgrid(W / TW, H / TH, 16 * CH);
        gauss_blur_fused_kernel<<<fgrid, 256, 0, stream>>>(x, w, out);
    }
}